// Round 14
// baseline (578.832 us; speedup 1.0000x reference)
//
#include <hip/hip_runtime.h>
#include <math.h>

#define H 4096
#define E 64
#define T_TOTAL 32768
#define TB 128            // tokens per block
#define NT 512            // 8 waves; lane = token-pair, wave = expert octet
#define KC 64             // K per LDS x-chunk
#define NCH (H / KC)      // 64 chunks
#define OFF_W 2097152
#define OFF_I 2162688

#define AS1 __attribute__((address_space(1)))
#define AS3 __attribute__((address_space(3)))

// Proven (R9/R12/R13 passed): 16B global->LDS DMA, linear LDS dest.
#define GLD16(SRC, DST)                                                      \
  __builtin_amdgcn_global_load_lds((const AS1 void*)(SRC), (AS3 void*)(DST), \
                                   16, 0, 0)

// R12-proven bank swizzle: logical col4 c of row r stored at slot c ^ swz(r).
__device__ __forceinline__ int swz(int r) { return (r ^ (r >> 4)) & 15; }

// One K4 step S (0..15). W slab WC (8 experts x K4, SGPR-resident), x regs
// XC0/XC1 (tokens lane, lane+64). Prefetches W(S+1) into WN (s_load, crosses
// into next chunk at S==15) and x(S+1) into XN0/XN1 (ds_read). The compiler
// places lgkmcnt(0) before the NEXT step's FMAs — after this step's 256-cyc
// FMA block — which is exactly the intended 1-step-latency window.
// Chain per (token,expert): ascending K, x/y/z/w — bit-identical to R1/R12.
#define XSTEP(S, WC, WN, XC0, XC1, XN0, XN1)                                 \
  do {                                                                       \
    const int kn = ((S) == 15)                                               \
                       ? ((c + 1 < NCH) ? (c + 1) * KC : c * KC)             \
                       : c * KC + ((S) + 1) * 4;                             \
    _Pragma("unroll")                                                        \
    for (int j = 0; j < 8; ++j)                                              \
      WN[j] = *(const float4*)(wbase + (size_t)j * H + kn);                  \
    if ((S) < 15) {                                                          \
      XN0 = *(const float4*)(xp + (xb0 ^ (((S) + 1) << 2)));                 \
      XN1 = *(const float4*)(xp + (xb1 ^ (((S) + 1) << 2)));                 \
    }                                                                        \
    _Pragma("unroll")                                                        \
    for (int j = 0; j < 8; ++j) {                                            \
      acc0[j] = fmaf((XC0).x, WC[j].x, acc0[j]);                             \
      acc0[j] = fmaf((XC0).y, WC[j].y, acc0[j]);                             \
      acc0[j] = fmaf((XC0).z, WC[j].z, acc0[j]);                             \
      acc0[j] = fmaf((XC0).w, WC[j].w, acc0[j]);                             \
      acc1[j] = fmaf((XC1).x, WC[j].x, acc1[j]);                             \
      acc1[j] = fmaf((XC1).y, WC[j].y, acc1[j]);                             \
      acc1[j] = fmaf((XC1).z, WC[j].z, acc1[j]);                             \
      acc1[j] = fmaf((XC1).w, WC[j].w, acc1[j]);                             \
    }                                                                        \
  } while (0)

__global__ __launch_bounds__(NT, 1)
void moe_router_kernel(const float* __restrict__ x,
                       const float* __restrict__ W,
                       float* __restrict__ out)
{
    // Double-buffered x tile [2][128 rows][64 K], slot-swizzled. 64 KB.
    __shared__ float xt[2][TB * KC];

    const int tid  = threadIdx.x;
    const int lane = tid & 63;                                   // token pair
    const int wid  = __builtin_amdgcn_readfirstlane(tid >> 6);   // expert octet
    const int e0   = 8 * wid;
    const int tok0 = blockIdx.x * TB;
    const int t0   = tok0 + lane;                                // token A
    const int t1   = t0 + 64;                                    // token B

    // Wave-uniform W base -> s_load/SGPR path (R8-proven scalarization).
    const float* wbase = W + (size_t)e0 * H;

    // ---- x DMA source map (rule 21: linear dest unit u, inverse-swz src) ----
    // unit u (0..2047): row = u>>4 (0..127), slot = u&15, col4 = slot^swz(row)
    const float* xsrc[4];
    int xdst[4];
#pragma unroll
    for (int k = 0; k < 4; ++k) {
        const int u   = tid + k * NT;
        const int row = u >> 4;
        const int c4  = (u & 15) ^ swz(row);
        xsrc[k] = x + (size_t)(tok0 + row) * H + (c4 << 2);
        xdst[k] = u * 4;
    }

    // LDS read bases (float idx; step s reads base ^ (4*s), 6-bit XOR-safe)
    const int xb0 = lane * KC + (swz(lane) << 2);
    const int xb1 = (lane + 64) * KC + (swz(lane + 64) << 2);

    float acc0[8], acc1[8];
#pragma unroll
    for (int j = 0; j < 8; ++j) { acc0[j] = 0.f; acc1[j] = 0.f; }

    // ---- prologue: DMA x chunk 0; prime W slab (c=0, s=0) ----
#pragma unroll
    for (int k = 0; k < 4; ++k) GLD16(xsrc[k], &xt[0][xdst[k]]);

    float4 wA[8], wB[8];
#pragma unroll
    for (int j = 0; j < 8; ++j)
        wA[j] = *(const float4*)(wbase + (size_t)j * H);

    __syncthreads();   // x chunk 0 resident (compiler drains vmcnt here)

    for (int c = 0; c < NCH; ++c) {
        const int b = c & 1;

        // DMA next x chunk into the other buffer (retired by end barrier)
        if (c + 1 < NCH) {
#pragma unroll
            for (int k = 0; k < 4; ++k)
                GLD16(xsrc[k] + (c + 1) * KC, &xt[b ^ 1][xdst[k]]);
        }

        const float* xp = &xt[b][0];
        // chunk-head x(0) reads (one exposed ds latency per chunk, ~120 cyc)
        float4 xc0 = *(const float4*)(xp + xb0);
        float4 xc1 = *(const float4*)(xp + xb1);
        float4 xd0, xd1;

        // 16 K4 steps; W ping-pongs wA/wB, x ping-pongs xc/xd.
        XSTEP(0,  wA, wB, xc0, xc1, xd0, xd1);
        XSTEP(1,  wB, wA, xd0, xd1, xc0, xc1);
        XSTEP(2,  wA, wB, xc0, xc1, xd0, xd1);
        XSTEP(3,  wB, wA, xd0, xd1, xc0, xc1);
        XSTEP(4,  wA, wB, xc0, xc1, xd0, xd1);
        XSTEP(5,  wB, wA, xd0, xd1, xc0, xc1);
        XSTEP(6,  wA, wB, xc0, xc1, xd0, xd1);
        XSTEP(7,  wB, wA, xd0, xd1, xc0, xc1);
        XSTEP(8,  wA, wB, xc0, xc1, xd0, xd1);
        XSTEP(9,  wB, wA, xd0, xd1, xc0, xc1);
        XSTEP(10, wA, wB, xc0, xc1, xd0, xd1);
        XSTEP(11, wB, wA, xd0, xd1, xc0, xc1);
        XSTEP(12, wA, wB, xc0, xc1, xd0, xd1);
        XSTEP(13, wB, wA, xd0, xd1, xc0, xc1);
        XSTEP(14, wA, wB, xc0, xc1, xd0, xd1);
        XSTEP(15, wB, wA, xd0, xd1, xc0, xc1);  // loads wA = next chunk W(0)

        __syncthreads();   // chunk c reads done; chunk c+1 DMA retired
    }

    // ---- logits out (from registers, bit-identical chain) ----
    {
        float* o0 = out + (size_t)t0 * E + e0;
        float* o1 = out + (size_t)t1 * E + e0;
        float4 v;
        v.x = acc0[0]; v.y = acc0[1]; v.z = acc0[2]; v.w = acc0[3];
        *(float4*)o0 = v;
        v.x = acc0[4]; v.y = acc0[5]; v.z = acc0[6]; v.w = acc0[7];
        *(float4*)(o0 + 4) = v;
        v.x = acc1[0]; v.y = acc1[1]; v.z = acc1[2]; v.w = acc1[3];
        *(float4*)o1 = v;
        v.x = acc1[4]; v.y = acc1[5]; v.z = acc1[6]; v.w = acc1[7];
        *(float4*)(o1 + 4) = v;
    }

    // ---- exchange for top-2 (reuse xt; 128 x 65 tile = 33.3 KB) ----
    float* lt = &xt[0][0];
#pragma unroll
    for (int j = 0; j < 8; ++j) {
        lt[lane * 65 + e0 + j]        = acc0[j];
        lt[(lane + 64) * 65 + e0 + j] = acc1[j];
    }
    __syncthreads();

    if (tid < TB) {
        const float* row = lt + tid * 65;
        float v1 = -INFINITY, v2 = -INFINITY;
        int i1 = 0, i2 = 0;
        for (int e = 0; e < E; ++e) {
            float v = row[e];
            if (v > v1)      { v2 = v1; i2 = i1; v1 = v; i1 = e; }
            else if (v > v2) { v2 = v;  i2 = e; }
        }
        // softmax -> top2 -> renorm == sigmoid of logit gap (Z cancels)
        float ee = expf(v2 - v1);
        float w1 = 1.0f / (1.0f + ee);
        float w2 = ee * w1;

        const size_t tok = (size_t)tok0 + tid;
        out[OFF_W + tok * 2]     = w1;
        out[OFF_W + tok * 2 + 1] = w2;
        out[OFF_I + tok * 2]     = (float)i1;
        out[OFF_I + tok * 2 + 1] = (float)i2;
    }
}

extern "C" void kernel_launch(void* const* d_in, const int* in_sizes, int n_in,
                              void* d_out, int out_size, void* d_ws, size_t ws_size,
                              hipStream_t stream) {
    const float* x = (const float*)d_in[0];
    const float* W = (const float*)d_in[1];
    float* out = (float*)d_out;

    dim3 grid(T_TOTAL / TB);   // 256 blocks -> 1 block/CU, 2 waves/SIMD
    dim3 block(NT);
    moe_router_kernel<<<grid, block, 0, stream>>>(x, W, out);
}

// Round 15
// 435.105 us; speedup vs baseline: 1.3303x; 1.3303x over previous
//
#include <hip/hip_runtime.h>
#include <math.h>

#define H 4096
#define E 64
#define T_TOTAL 32768
#define TB 128            // tokens per block
#define NT 256            // 4 waves; tg = tid&15 (token octet), eg = tid>>4 (expert quad)
#define KC 64             // K per chunk
#define NCH (H / KC)      // 64 chunks
#define OFF_W 2097152
#define OFF_I 2162688

#define AS1 __attribute__((address_space(1)))
#define AS3 __attribute__((address_space(3)))

// Proven (R9/R12/R13 passed): 16B global->LDS DMA, linear LDS dest.
#define GLD16(SRC, DST)                                                      \
  __builtin_amdgcn_global_load_lds((const AS1 void*)(SRC), (AS3 void*)(DST), \
                                   16, 0, 0)

// R12-proven bank swizzle: logical col4 c of row r stored at slot c ^ swz(r).
__device__ __forceinline__ int swz(int r) { return (r ^ (r >> 4)) & 15; }

// Issue step-S operand reads into register set (XV, WV).
#define LOADS(XV, WV, S)                                                     \
  do {                                                                       \
    _Pragma("unroll")                                                        \
    for (int i = 0; i < 8; ++i)                                              \
      XV[i] = *(const float4*)(xp + (xbase[i] ^ ((S) << 2)));                \
    _Pragma("unroll")                                                        \
    for (int j = 0; j < 4; ++j)                                              \
      WV[j] = *(const float4*)(wp + (wbase[j] ^ ((S) << 2)));                \
  } while (0)

// 128 FMAs on a resident register set. Ascending-K, x/y/z/w per
// (token,expert) — bit-identical chain to the verified R1/R12/R13 kernels.
#define FMAS(XV, WV)                                                         \
  do {                                                                       \
    _Pragma("unroll")                                                        \
    for (int i = 0; i < 8; ++i)                                              \
      _Pragma("unroll")                                                      \
      for (int j = 0; j < 4; ++j) {                                          \
        acc[i][j] = fmaf(XV[i].x, WV[j].x, acc[i][j]);                       \
        acc[i][j] = fmaf(XV[i].y, WV[j].y, acc[i][j]);                       \
        acc[i][j] = fmaf(XV[i].z, WV[j].z, acc[i][j]);                       \
        acc[i][j] = fmaf(XV[i].w, WV[j].w, acc[i][j]);                       \
      }                                                                      \
  } while (0)

// Pipelined pair: issue s+1 into the other set, then FMA set s.
#define PSTEP(SNEXT, XC, WC, XN, WN)                                         \
  do { LOADS(XN, WN, SNEXT); FMAS(XC, WC); } while (0)

__global__ __launch_bounds__(NT, 1)   // 1 block/CU -> VGPR cap 512, no spill
void moe_router_kernel(const float* __restrict__ x,
                       const float* __restrict__ W,
                       float* __restrict__ out)
{
    // Double-buffered tiles, [rows][16 slots of 16B], slot-swizzled. 96 KB.
    __shared__ float xt[2][TB * KC];   // 2 x 32 KB
    __shared__ float wt[2][E * KC];    // 2 x 16 KB

    const int tid  = threadIdx.x;
    const int tg   = tid & 15;          // token octet 8tg..8tg+7
    const int eg   = tid >> 4;          // expert quad 4eg..4eg+3
    const int tok0 = blockIdx.x * TB;

    // ---- DMA source maps (rule 21: linear dest unit u, inverse-swz source) ----
    const float* xsrc[8];
    int xdst[8];
#pragma unroll
    for (int k = 0; k < 8; ++k) {
        const int u   = tid + k * NT;
        const int row = u >> 4;
        const int c4  = (u & 15) ^ swz(row);
        xsrc[k] = x + (size_t)(tok0 + row) * H + (c4 << 2);
        xdst[k] = u * 4;
    }
    const float* wsrc[4];
    int wdst[4];
#pragma unroll
    for (int k = 0; k < 4; ++k) {
        const int u   = tid + k * NT;
        const int row = u >> 4;
        const int c4  = (u & 15) ^ swz(row);
        wsrc[k] = W + (size_t)row * H + (c4 << 2);
        wdst[k] = u * 4;
    }

    // ---- LDS read bases (float idx; step s reads base ^ (4*s), carry-free) ----
    int xbase[8], wbase[4];
#pragma unroll
    for (int i = 0; i < 8; ++i) {
        const int r = 8 * tg + i;
        xbase[i] = r * KC + (swz(r) << 2);
    }
#pragma unroll
    for (int j = 0; j < 4; ++j) {
        const int r = 4 * eg + j;
        wbase[j] = r * KC + (swz(r) << 2);
    }

    float acc[8][4];
#pragma unroll
    for (int i = 0; i < 8; ++i)
#pragma unroll
        for (int j = 0; j < 4; ++j) acc[i][j] = 0.f;

    // ---- prologue: DMA chunk 0 into buffer 0 ----
#pragma unroll
    for (int k = 0; k < 8; ++k) GLD16(xsrc[k], &xt[0][xdst[k]]);
#pragma unroll
    for (int k = 0; k < 4; ++k) GLD16(wsrc[k], &wt[0][wdst[k]]);
    __syncthreads();   // compiler emits vmcnt(0) drain before s_barrier

    for (int c = 0; c < NCH; ++c) {
        const int b = c & 1;

        // DMA next chunk into the other buffer (retired by the barrier below)
        if (c + 1 < NCH) {
#pragma unroll
            for (int k = 0; k < 8; ++k)
                GLD16(xsrc[k] + (c + 1) * KC, &xt[b ^ 1][xdst[k]]);
#pragma unroll
            for (int k = 0; k < 4; ++k)
                GLD16(wsrc[k] + (c + 1) * KC, &wt[b ^ 1][wdst[k]]);
        }

        // ---- 16 K4 steps, software-pipelined 1 step ahead (ping-pong) ----
        const float* xp = &xt[b][0];
        const float* wp = &wt[b][0];
        float4 xva[8], wva[4], xvb[8], wvb[4];

        LOADS(xva, wva, 0);
        PSTEP(1,  xva, wva, xvb, wvb);
        PSTEP(2,  xvb, wvb, xva, wva);
        PSTEP(3,  xva, wva, xvb, wvb);
        PSTEP(4,  xvb, wvb, xva, wva);
        PSTEP(5,  xva, wva, xvb, wvb);
        PSTEP(6,  xvb, wvb, xva, wva);
        PSTEP(7,  xva, wva, xvb, wvb);
        PSTEP(8,  xvb, wvb, xva, wva);
        PSTEP(9,  xva, wva, xvb, wvb);
        PSTEP(10, xvb, wvb, xva, wva);
        PSTEP(11, xva, wva, xvb, wvb);
        PSTEP(12, xvb, wvb, xva, wva);
        PSTEP(13, xva, wva, xvb, wvb);
        PSTEP(14, xvb, wvb, xva, wva);
        PSTEP(15, xva, wva, xvb, wvb);
        FMAS(xvb, wvb);                 // step 15 (no further load)

        __syncthreads();   // chunk c done everywhere; chunk c+1 DMA retired
    }

    // ---- logits out (coalesced float4 per owned token) ----
#pragma unroll
    for (int i = 0; i < 8; ++i) {
        float4 v; v.x = acc[i][0]; v.y = acc[i][1]; v.z = acc[i][2]; v.w = acc[i][3];
        *(float4*)(out + (size_t)(tok0 + 8 * tg + i) * E + 4 * eg) = v;
    }

    // ---- exchange for top-2 (reuse xt; 128 x 65 tile = 33.3 KB) ----
    float* lt = &xt[0][0];
#pragma unroll
    for (int i = 0; i < 8; ++i)
#pragma unroll
        for (int j = 0; j < 4; ++j)
            lt[(8 * tg + i) * 65 + 4 * eg + j] = acc[i][j];
    __syncthreads();

    if (tid < TB) {
        const float* row = lt + tid * 65;
        float v1 = -INFINITY, v2 = -INFINITY;
        int i1 = 0, i2 = 0;
        for (int e = 0; e < E; ++e) {
            float v = row[e];
            if (v > v1)      { v2 = v1; i2 = i1; v1 = v; i1 = e; }
            else if (v > v2) { v2 = v;  i2 = e; }
        }
        // softmax -> top2 -> renorm == sigmoid of logit gap (Z cancels)
        float ee = expf(v2 - v1);
        float w1 = 1.0f / (1.0f + ee);
        float w2 = ee * w1;

        const size_t tok = (size_t)tok0 + tid;
        out[OFF_W + tok * 2]     = w1;
        out[OFF_W + tok * 2 + 1] = w2;
        out[OFF_I + tok * 2]     = (float)i1;
        out[OFF_I + tok * 2 + 1] = (float)i2;
    }
}

extern "C" void kernel_launch(void* const* d_in, const int* in_sizes, int n_in,
                              void* d_out, int out_size, void* d_ws, size_t ws_size,
                              hipStream_t stream) {
    const float* x = (const float*)d_in[0];
    const float* W = (const float*)d_in[1];
    float* out = (float*)d_out;

    dim3 grid(T_TOTAL / TB);   // 256 blocks -> exactly 1 block/CU
    dim3 block(NT);
    moe_router_kernel<<<grid, block, 0, stream>>>(x, W, out);
}

// Round 16
// 371.336 us; speedup vs baseline: 1.5588x; 1.1717x over previous
//
#include <hip/hip_runtime.h>
#include <math.h>

#define H 4096
#define E 64
#define T_TOTAL 32768
#define TB 64             // tokens per block
#define NT 256            // 4 waves; tg = tid&15 (token quad), eg = tid>>4 (expert quad)
#define KC 64             // K per chunk
#define NCH (H / KC)      // 64 chunks
#define OFF_W 2097152
#define OFF_I 2162688

#define AS1 __attribute__((address_space(1)))
#define AS3 __attribute__((address_space(3)))

// Proven (R9/R12/R13/R15 passed): 16B global->LDS DMA, linear LDS dest.
#define GLD16(SRC, DST)                                                      \
  __builtin_amdgcn_global_load_lds((const AS1 void*)(SRC), (AS3 void*)(DST), \
                                   16, 0, 0)

// R12-proven bank swizzle: logical col4 c of row r stored at slot c ^ swz(r).
__device__ __forceinline__ int swz(int r) { return (r ^ (r >> 4)) & 15; }

// Issue step-S operand reads: x from LDS (pipe 1), W from global/L1 (pipe 2).
#define LOADS(XV, WV, S)                                                     \
  do {                                                                       \
    _Pragma("unroll")                                                        \
    for (int i = 0; i < 4; ++i)                                              \
      XV[i] = *(const float4*)(xp + (xbase[i] ^ ((S) << 2)));                \
    _Pragma("unroll")                                                        \
    for (int j = 0; j < 4; ++j)                                              \
      WV[j] = *(const float4*)(wrow[j] + kco + ((S) << 2));                  \
  } while (0)

// 64 FMAs on a resident register set. Ascending-K, x/y/z/w per
// (token,expert) — bit-identical chain to the verified R1/R12/R13 kernels.
#define FMAS(XV, WV)                                                         \
  do {                                                                       \
    _Pragma("unroll")                                                        \
    for (int i = 0; i < 4; ++i)                                              \
      _Pragma("unroll")                                                      \
      for (int j = 0; j < 4; ++j) {                                          \
        acc[i][j] = fmaf(XV[i].x, WV[j].x, acc[i][j]);                       \
        acc[i][j] = fmaf(XV[i].y, WV[j].y, acc[i][j]);                       \
        acc[i][j] = fmaf(XV[i].z, WV[j].z, acc[i][j]);                       \
        acc[i][j] = fmaf(XV[i].w, WV[j].w, acc[i][j]);                       \
      }                                                                      \
  } while (0)

// Pipelined pair: issue s+1 into the other set, then FMA set s.
#define PSTEP(SNEXT, XC, WC, XN, WN)                                         \
  do { LOADS(XN, WN, SNEXT); FMAS(XC, WC); } while (0)

__global__ __launch_bounds__(NT, 2)
void moe_router_kernel(const float* __restrict__ x,
                       const float* __restrict__ W,
                       float* __restrict__ out)
{
    // Double-buffered x tile only (W comes from L1). 32 KB -> 2 blocks/CU.
    __shared__ float xt[2][TB * KC];

    const int tid  = threadIdx.x;
    const int tg   = tid & 15;          // token quad 4tg..4tg+3
    const int eg   = tid >> 4;          // expert quad 4eg..4eg+3
    const int tok0 = blockIdx.x * TB;

    // ---- x DMA source map (rule 21: linear dest unit u, inverse-swz src) ----
    const float* xsrc[4];
    int xdst[4];
#pragma unroll
    for (int k = 0; k < 4; ++k) {
        const int u   = tid + k * NT;
        const int row = u >> 4;
        const int c4  = (u & 15) ^ swz(row);
        xsrc[k] = x + (size_t)(tok0 + row) * H + (c4 << 2);
        xdst[k] = u * 4;
    }

    // ---- LDS read bases (step s reads base ^ (4*s), carry-free 6-bit XOR) ----
    int xbase[4];
#pragma unroll
    for (int i = 0; i < 4; ++i) {
        const int r = 4 * tg + i;
        xbase[i] = r * KC + (swz(r) << 2);
    }

    // ---- W global row pointers (per-lane distinct -> vector loads, L1-hot) ----
    const float* wrow[4];
#pragma unroll
    for (int j = 0; j < 4; ++j)
        wrow[j] = W + (size_t)(4 * eg + j) * H;

    float acc[4][4];
#pragma unroll
    for (int i = 0; i < 4; ++i)
#pragma unroll
        for (int j = 0; j < 4; ++j) acc[i][j] = 0.f;

    // ---- prologue: DMA x chunk 0 into buffer 0 ----
#pragma unroll
    for (int k = 0; k < 4; ++k) GLD16(xsrc[k], &xt[0][xdst[k]]);
    __syncthreads();   // compiler drains vmcnt before s_barrier

    for (int c = 0; c < NCH; ++c) {
        const int b = c & 1;
        const int kco = c * KC;

        // DMA next x chunk into the other buffer (retired by barrier below)
        if (c + 1 < NCH) {
#pragma unroll
            for (int k = 0; k < 4; ++k)
                GLD16(xsrc[k] + (c + 1) * KC, &xt[b ^ 1][xdst[k]]);
        }

        // ---- 16 K4 steps, 1-step ping-pong (x: LDS pipe, W: L1 pipe) ----
        const float* xp = &xt[b][0];
        float4 xva[4], wva[4], xvb[4], wvb[4];

        LOADS(xva, wva, 0);
        PSTEP(1,  xva, wva, xvb, wvb);
        PSTEP(2,  xvb, wvb, xva, wva);
        PSTEP(3,  xva, wva, xvb, wvb);
        PSTEP(4,  xvb, wvb, xva, wva);
        PSTEP(5,  xva, wva, xvb, wvb);
        PSTEP(6,  xvb, wvb, xva, wva);
        PSTEP(7,  xva, wva, xvb, wvb);
        PSTEP(8,  xvb, wvb, xva, wva);
        PSTEP(9,  xva, wva, xvb, wvb);
        PSTEP(10, xvb, wvb, xva, wva);
        PSTEP(11, xva, wva, xvb, wvb);
        PSTEP(12, xvb, wvb, xva, wva);
        PSTEP(13, xva, wva, xvb, wvb);
        PSTEP(14, xvb, wvb, xva, wva);
        PSTEP(15, xva, wva, xvb, wvb);
        FMAS(xvb, wvb);                 // step 15

        __syncthreads();   // chunk c reads done; chunk c+1 DMA retired
    }

    // ---- logits out (coalesced float4 per owned token) ----
#pragma unroll
    for (int i = 0; i < 4; ++i) {
        float4 v; v.x = acc[i][0]; v.y = acc[i][1]; v.z = acc[i][2]; v.w = acc[i][3];
        *(float4*)(out + (size_t)(tok0 + 4 * tg + i) * E + 4 * eg) = v;
    }

    // ---- exchange for top-2 (reuse xt; 64 x 65 tile) ----
    float* lt = &xt[0][0];
#pragma unroll
    for (int i = 0; i < 4; ++i)
#pragma unroll
        for (int j = 0; j < 4; ++j)
            lt[(4 * tg + i) * 65 + 4 * eg + j] = acc[i][j];
    __syncthreads();

    if (tid < TB) {
        const float* row = lt + tid * 65;
        float v1 = -INFINITY, v2 = -INFINITY;
        int i1 = 0, i2 = 0;
        for (int e = 0; e < E; ++e) {
            float v = row[e];
            if (v > v1)      { v2 = v1; i2 = i1; v1 = v; i1 = e; }
            else if (v > v2) { v2 = v;  i2 = e; }
        }
        // softmax -> top2 -> renorm == sigmoid of logit gap (Z cancels)
        float ee = expf(v2 - v1);
        float w1 = 1.0f / (1.0f + ee);
        float w2 = ee * w1;

        const size_t tok = (size_t)tok0 + tid;
        out[OFF_W + tok * 2]     = w1;
        out[OFF_W + tok * 2 + 1] = w2;
        out[OFF_I + tok * 2]     = (float)i1;
        out[OFF_I + tok * 2 + 1] = (float)i2;
    }
}

extern "C" void kernel_launch(void* const* d_in, const int* in_sizes, int n_in,
                              void* d_out, int out_size, void* d_ws, size_t ws_size,
                              hipStream_t stream) {
    const float* x = (const float*)d_in[0];
    const float* W = (const float*)d_in[1];
    float* out = (float*)d_out;

    dim3 grid(T_TOTAL / TB);   // 512 blocks -> 2 blocks/CU, 2 waves/SIMD
    dim3 block(NT);
    moe_router_kernel<<<grid, block, 0, stream>>>(x, W, out);
}